// Round 1
// baseline (442.351 us; speedup 1.0000x reference)
//
#include <hip/hip_runtime.h>

// GNN layer: messages = relu(NF @ Wm^T + bm); agg = (adj @ messages)/deg; GRU(agg, NF)
// N=8192, D=128. Memory-bound on adj (268 MB int32). bf16 MFMA 16x16x32 throughout.

#define NN 8192
#define DIM 128
#define LSTR 136  // 128 + 8 bf16 pad: breaks bank conflicts, keeps 16B align (272B rows)

typedef __bf16 bf16x8 __attribute__((ext_vector_type(8)));
typedef float f32x4 __attribute__((ext_vector_type(4)));

__device__ __forceinline__ unsigned short f2bf(float f) {
  union { float f; unsigned u; } v; v.f = f;
  unsigned r = v.u + 0x7FFF + ((v.u >> 16) & 1);  // RNE
  return (unsigned short)(r >> 16);
}
__device__ __forceinline__ float sigmoidf_(float x) {
  return 1.0f / (1.0f + __expf(-x));
}
__device__ __forceinline__ float tanhf_(float x) {
  float e = __expf(-2.0f * fabsf(x));        // stable both sides
  float r = (1.0f - e) / (1.0f + e);
  return x < 0.0f ? -r : r;
}

// ---------------- K1: messages = relu(NF @ Wm^T + bm), stored transposed msgT[o][m] (bf16)
__global__ __launch_bounds__(256) void k1_msg(
    const float* __restrict__ nf, const float* __restrict__ w_msg,
    const float* __restrict__ b_msg, unsigned short* __restrict__ msgT) {
  __shared__ unsigned short wm[128 * LSTR];   // wm[o][k] bf16
  __shared__ unsigned short nfl[64 * LSTR];   // nf tile [m][k] bf16
  const int t = threadIdx.x;
  const int m0 = blockIdx.x * 64;
  for (int i = t; i < 128 * 128; i += 256)
    wm[(i >> 7) * LSTR + (i & 127)] = f2bf(w_msg[i]);
  for (int i = t; i < 64 * 128; i += 256)
    nfl[(i >> 7) * LSTR + (i & 127)] = f2bf(nf[m0 * 128 + i]);
  __syncthreads();
  const int lane = t & 63, wave = t >> 6;
  const int quad = lane >> 4, l16 = lane & 15;
  const int rt = wave;  // 4 waves x 16 rows = 64 rows
  f32x4 acc[8];
  for (int j = 0; j < 8; ++j) acc[j] = (f32x4){0.f, 0.f, 0.f, 0.f};
  for (int kk = 0; kk < 4; ++kk) {
    bf16x8 a = *(const bf16x8*)&nfl[(rt * 16 + l16) * LSTR + kk * 32 + quad * 8];
    for (int ct = 0; ct < 8; ++ct) {
      bf16x8 b = *(const bf16x8*)&wm[(ct * 16 + l16) * LSTR + kk * 32 + quad * 8];
      acc[ct] = __builtin_amdgcn_mfma_f32_16x16x32_bf16(a, b, acc[ct], 0, 0, 0);
    }
  }
  for (int ct = 0; ct < 8; ++ct) {
    const int o = ct * 16 + l16;
    const float bias = b_msg[o];
    for (int r = 0; r < 4; ++r) {
      const int m = m0 + rt * 16 + quad * 4 + r;
      float v = fmaxf(acc[ct][r] + bias, 0.0f);
      msgT[o * NN + m] = f2bf(v);
    }
  }
}

// ---------------- K2: agg[m][o] = (sum_k adj[m][k]*msg[k][o]) / max(deg[m],1), bf16 out
// 256 WGs x 512 thr (8 waves). M-tile 32, BK 128, register-prefetch double buffer.
__global__ __launch_bounds__(512) void k2_agg(
    const int* __restrict__ adj, const unsigned short* __restrict__ msgT,
    unsigned short* __restrict__ agg) {
  __shared__ unsigned short adjL[32 * LSTR];   // A tile [m][k] bf16 (0/1)
  __shared__ unsigned short msgL[128 * LSTR];  // B tile [o][k] bf16 (from msgT)
  __shared__ int degS[32];
  const int t = threadIdx.x;
  const int m0 = blockIdx.x * 32;
  if (t < 32) degS[t] = 0;

  // adj staging: 32 rows x 128 ints = 1024 int4; thread t does rows (t>>5) and 16+(t>>5)
  const int ar = t >> 5;         // 0..15
  const int as = t & 31;         // int4 segment within row
  // msg staging: 128 rows x 128 bf16 = 2048 x int4(8bf16); rows mn, mn+32, mn+64, mn+96
  const int mn = t >> 4;         // 0..31
  const int mko = (t & 15) * 8;  // element offset in k

  const int* aB0 = adj + (m0 + ar) * NN + as * 4;
  const int* aB1 = aB0 + 16 * NN;
  const unsigned short* mB0 = msgT + (mn +  0) * NN + mko;
  const unsigned short* mB1 = msgT + (mn + 32) * NN + mko;
  const unsigned short* mB2 = msgT + (mn + 64) * NN + mko;
  const unsigned short* mB3 = msgT + (mn + 96) * NN + mko;

  int deg0 = 0, deg1 = 0;
  int4 pa0 = *(const int4*)aB0;
  int4 pa1 = *(const int4*)aB1;
  int4 pm0 = *(const int4*)mB0;
  int4 pm1 = *(const int4*)mB1;
  int4 pm2 = *(const int4*)mB2;
  int4 pm3 = *(const int4*)mB3;

  const int lane = t & 63, wave = t >> 6;
  const int quad = lane >> 4, l16 = lane & 15;
  const int rt = wave >> 2;              // waves 0-3: rows 0-15; 4-7: rows 16-31
  const int ct0 = (wave & 3) * 2, ct1 = ct0 + 1;
  f32x4 acc0 = {0.f, 0.f, 0.f, 0.f}, acc1 = {0.f, 0.f, 0.f, 0.f};

  const int aOff  = (rt * 16 + l16) * LSTR + quad * 8;
  const int bOff0 = (ct0 * 16 + l16) * LSTR + quad * 8;
  const int bOff1 = (ct1 * 16 + l16) * LSTR + quad * 8;

  for (int c = 0; c < 64; ++c) {
    // drain prefetch regs -> LDS (int 0/1 -> bf16), accumulate degree for free
    ushort4 w0, w1;
    w0.x = pa0.x ? 0x3F80 : 0; w0.y = pa0.y ? 0x3F80 : 0;
    w0.z = pa0.z ? 0x3F80 : 0; w0.w = pa0.w ? 0x3F80 : 0;
    w1.x = pa1.x ? 0x3F80 : 0; w1.y = pa1.y ? 0x3F80 : 0;
    w1.z = pa1.z ? 0x3F80 : 0; w1.w = pa1.w ? 0x3F80 : 0;
    deg0 += pa0.x + pa0.y + pa0.z + pa0.w;
    deg1 += pa1.x + pa1.y + pa1.z + pa1.w;
    *(ushort4*)&adjL[ar * LSTR + as * 4] = w0;
    *(ushort4*)&adjL[(16 + ar) * LSTR + as * 4] = w1;
    *(int4*)&msgL[(mn +  0) * LSTR + mko] = pm0;
    *(int4*)&msgL[(mn + 32) * LSTR + mko] = pm1;
    *(int4*)&msgL[(mn + 64) * LSTR + mko] = pm2;
    *(int4*)&msgL[(mn + 96) * LSTR + mko] = pm3;
    __syncthreads();
    if (c < 63) {  // issue next chunk's global loads before compute (latency hiding)
      const int k0 = (c + 1) * 128;
      pa0 = *(const int4*)(aB0 + k0);
      pa1 = *(const int4*)(aB1 + k0);
      pm0 = *(const int4*)(mB0 + k0);
      pm1 = *(const int4*)(mB1 + k0);
      pm2 = *(const int4*)(mB2 + k0);
      pm3 = *(const int4*)(mB3 + k0);
    }
    for (int kk = 0; kk < 4; ++kk) {
      bf16x8 a  = *(const bf16x8*)&adjL[aOff  + kk * 32];
      bf16x8 b0 = *(const bf16x8*)&msgL[bOff0 + kk * 32];
      bf16x8 b1 = *(const bf16x8*)&msgL[bOff1 + kk * 32];
      acc0 = __builtin_amdgcn_mfma_f32_16x16x32_bf16(a, b0, acc0, 0, 0, 0);
      acc1 = __builtin_amdgcn_mfma_f32_16x16x32_bf16(a, b1, acc1, 0, 0, 0);
    }
    __syncthreads();
  }
  atomicAdd(&degS[ar], deg0);
  atomicAdd(&degS[16 + ar], deg1);
  __syncthreads();
  for (int r = 0; r < 4; ++r) {
    const int rowL = rt * 16 + quad * 4 + r;
    const float inv = 1.0f / fmaxf((float)degS[rowL], 1.0f);
    const int m = m0 + rowL;
    agg[m * 128 + ct0 * 16 + l16] = f2bf(acc0[r] * inv);
    agg[m * 128 + ct1 * 16 + l16] = f2bf(acc1[r] * inv);
  }
}

// ---------------- K3: fused GRU. Chunks o in {r(0), n(2), z(1)}; r lives in regs
// (its MFMA C-layout matches the n-chunk accumulators element-for-element).
__global__ __launch_bounds__(256) void k3_gru(
    const float* __restrict__ nf, const unsigned short* __restrict__ agg,
    const float* __restrict__ w_ih, const float* __restrict__ w_hh,
    const float* __restrict__ b_ih, const float* __restrict__ b_hh,
    float* __restrict__ out) {
  __shared__ unsigned short aggL[32 * LSTR];
  __shared__ unsigned short nfL[32 * LSTR];
  __shared__ unsigned short wL[128 * LSTR];
  const int t = threadIdx.x;
  const int m0 = blockIdx.x * 32;
  for (int i = t; i < 512; i += 256) {          // agg is already bf16: int4 copies
    const int r = i >> 4, ko = (i & 15) * 8;
    *(int4*)&aggL[r * LSTR + ko] = *(const int4*)&agg[(m0 + r) * 128 + ko];
  }
  for (int i = t; i < 32 * 128; i += 256)
    nfL[(i >> 7) * LSTR + (i & 127)] = f2bf(nf[(m0 + (i >> 7)) * 128 + (i & 127)]);

  const int lane = t & 63, wave = t >> 6;
  const int quad = lane >> 4, l16 = lane & 15;
  const int rt = wave >> 1;            // 2 row-tiles
  const int cb = (wave & 1) * 4;       // 4 col-tiles per wave
  const int aOff = (rt * 16 + l16) * LSTR + quad * 8;

  float gate[4][4];
  const int order[3] = {0, 2, 1};      // r -> n -> z
  for (int ci = 0; ci < 3; ++ci) {
    const int c = order[ci];
    __syncthreads();  // prior readers of wL done (and agg/nf staging visible)
    for (int i = t; i < 128 * 128; i += 256)
      wL[(i >> 7) * LSTR + (i & 127)] = f2bf(w_ih[c * 16384 + i]);
    __syncthreads();
    f32x4 ai[4];
    {
      bf16x8 a[4];
      for (int kk = 0; kk < 4; ++kk) a[kk] = *(const bf16x8*)&aggL[aOff + kk * 32];
      for (int j = 0; j < 4; ++j) {
        f32x4 acc = {0.f, 0.f, 0.f, 0.f};
        const int ct = cb + j;
        for (int kk = 0; kk < 4; ++kk) {
          bf16x8 b = *(const bf16x8*)&wL[(ct * 16 + l16) * LSTR + kk * 32 + quad * 8];
          acc = __builtin_amdgcn_mfma_f32_16x16x32_bf16(a[kk], b, acc, 0, 0, 0);
        }
        ai[j] = acc;
      }
    }
    __syncthreads();
    for (int i = t; i < 128 * 128; i += 256)
      wL[(i >> 7) * LSTR + (i & 127)] = f2bf(w_hh[c * 16384 + i]);
    __syncthreads();
    f32x4 ah[4];
    {
      bf16x8 a[4];
      for (int kk = 0; kk < 4; ++kk) a[kk] = *(const bf16x8*)&nfL[aOff + kk * 32];
      for (int j = 0; j < 4; ++j) {
        f32x4 acc = {0.f, 0.f, 0.f, 0.f};
        const int ct = cb + j;
        for (int kk = 0; kk < 4; ++kk) {
          bf16x8 b = *(const bf16x8*)&wL[(ct * 16 + l16) * LSTR + kk * 32 + quad * 8];
          acc = __builtin_amdgcn_mfma_f32_16x16x32_bf16(a[kk], b, acc, 0, 0, 0);
        }
        ah[j] = acc;
      }
    }
    for (int j = 0; j < 4; ++j) {
      const int col = (cb + j) * 16 + l16;
      const float bi = b_ih[c * 128 + col];
      const float bh = b_hh[c * 128 + col];
      for (int r = 0; r < 4; ++r) {
        const float gi = ai[j][r] + bi;
        const float gh = ah[j][r] + bh;
        if (c == 0) {
          gate[j][r] = sigmoidf_(gi + gh);                 // r
        } else if (c == 2) {
          gate[j][r] = tanhf_(gi + gate[j][r] * gh);       // n = tanh(i_n + r*h_n)
        } else {
          const float z = sigmoidf_(gi + gh);
          const int m = m0 + rt * 16 + quad * 4 + r;
          const float h = nf[m * 128 + col];
          out[m * 128 + col] = (1.0f - z) * gate[j][r] + z * h;
        }
      }
    }
  }
}

extern "C" void kernel_launch(void* const* d_in, const int* in_sizes, int n_in,
                              void* d_out, int out_size, void* d_ws, size_t ws_size,
                              hipStream_t stream) {
  const float* nf   = (const float*)d_in[0];
  const int*   adj  = (const int*)d_in[1];
  const float* wmsg = (const float*)d_in[2];
  const float* bmsg = (const float*)d_in[3];
  const float* wih  = (const float*)d_in[4];
  const float* whh  = (const float*)d_in[5];
  const float* bih  = (const float*)d_in[6];
  const float* bhh  = (const float*)d_in[7];
  float* out = (float*)d_out;

  unsigned short* msgT = (unsigned short*)d_ws;       // bf16 [128][8192]  (2 MB)
  unsigned short* aggB = msgT + (size_t)NN * DIM;     // bf16 [8192][128]  (2 MB)

  k1_msg<<<NN / 64, 256, 0, stream>>>(nf, wmsg, bmsg, msgT);
  k2_agg<<<NN / 32, 512, 0, stream>>>(adj, msgT, aggB);
  k3_gru<<<NN / 32, 256, 0, stream>>>(nf, aggB, wih, whh, bih, bhh, out);
}